// Round 9
// baseline (326.044 us; speedup 1.0000x reference)
//
#include <hip/hip_runtime.h>
#include <math.h>

#define L_SEQ 32768
#define PL 16384      // u16 per LDS plane (128x128 swizzled)
#define PLG 32768     // u16 plane stride for ALL global chain matrices

typedef unsigned short u16;
typedef float f32x4 __attribute__((ext_vector_type(4)));
typedef short bf16x8 __attribute__((ext_vector_type(8)));
typedef u16 u16x4 __attribute__((ext_vector_type(4)));

__device__ __forceinline__ u16 f2bf(float x) {
  unsigned u = __float_as_uint(x);
  u = u + 0x7FFFu + ((u >> 16) & 1u);
  return (u16)(u >> 16);
}
__device__ __forceinline__ float bf2f(u16 h) { return __uint_as_float(((unsigned)h) << 16); }
__device__ __forceinline__ int MIDX(int r, int c) { return (r << 7) + (c ^ ((r & 7) << 3)); }
__device__ __forceinline__ f32x4 MF(bf16x8 a, bf16x8 b, f32x4 c) {
  return __builtin_amdgcn_mfma_f32_16x16x32_bf16(a, b, c, 0, 0, 0);
}
__device__ __forceinline__ void gfrag(const u16* g, int row, int kp, bf16x8& h, bf16x8& l) {
  h = *(const bf16x8*)(g + row * 128 + kp);
  l = *(const bf16x8*)(g + PLG + row * 128 + kp);
}
__device__ __forceinline__ void lfrag(const u16* base, int row, int kp, bf16x8& h, bf16x8& l) {
  h = *(const bf16x8*)(base + MIDX(row, kp));
  l = *(const bf16x8*)(base + PL + MIDX(row, kp));
}
__device__ __forceinline__ void pack4(const float* v, u16x4& hi, u16x4& lo) {
#pragma unroll
  for (int j = 0; j < 4; ++j) {
    u16 h = f2bf(v[j]);
    hi[j] = h;
    lo[j] = f2bf(v[j] - bf2f(h));
  }
}

// ---------------------------------------------------------------------------
// One fused step on a 1024-thread block (16 waves, 4x4 grid of 32x32 tiles).
// Main product C = A(128x128)*B(128x128), fp32 via 3 bf16 MFMAs (hi/lo planes).
// MK: 0 none | 1 in-place slot update (acc->Bt, accT->M) | 2 same + MODE4
//     (v = c3*(v + U12) - I, U12 from gU rows) with A from gU global |
//     3 K-step: A global rows, B global rows, accT -> f32 Kv
// ERS extra-row slots (rows er = wr*16 + f*64 + la): rides S-dbl / U12 on the
//     shared B operand; out rows to gOe at eR0+er; M2 adds T+T2+I (gT1,gT2x).
// HEC extra cols (ec = wc*32 + e*16 + la): rides R-dbl on the shared A
//     operand, B streamed from gBe rows; out transposed to gOc at eC0+ec.
// DUMP: also write accT rows to gDump (row-major) - used to spill T2.
// Garbage reads for masked extras are harmless: MFMA col c / row r depends
// only on lane c's B / row r's A; unmasked lanes never get written.
// ---------------------------------------------------------------------------
template<int MK, int ERS, bool HEC, bool M2, bool DUMP>
__device__ void step(u16* lds,
                     const u16* gAm, const u16* gBm, const u16* gU, float c3,
                     float* KvO, int kc0, u16* gDump,
                     int ER, const u16* gAe, u16* gOe, int eR0,
                     const u16* gT1, const u16* gT2x,
                     int EC, const u16* gBe, u16* gOc, int eC0) {
  u16* Mb = lds;
  u16* Tb = lds + 2 * PL;
  const int t = threadIdx.x, lane = t & 63, la = lane & 15, g = lane >> 4;
  const int w = t >> 6, wr = w >> 2, wc = w & 3;
  const int r0 = wr << 5, c0 = wc << 5;
  constexpr int ERN = (ERS > 0) ? ERS : 1;

  __syncthreads();  // operands (LDS slot + prior global writes) ready

  f32x4 acc[2][2], accT[2][2], accE[ERN][2], accC[2][2];
#pragma unroll
  for (int i = 0; i < 2; ++i)
#pragma unroll
    for (int j = 0; j < 2; ++j) {
      acc[i][j] = (f32x4){0.f, 0.f, 0.f, 0.f};
      accT[i][j] = (f32x4){0.f, 0.f, 0.f, 0.f};
      accC[i][j] = (f32x4){0.f, 0.f, 0.f, 0.f};
    }
#pragma unroll
  for (int f = 0; f < ERN; ++f)
#pragma unroll
    for (int j = 0; j < 2; ++j) accE[f][j] = (f32x4){0.f, 0.f, 0.f, 0.f};

#pragma unroll
  for (int kb = 0; kb < 4; ++kb) {
    const int kp = (kb << 5) + (g << 3);
    bf16x8 Ah[2], Al[2], Bh[2], Bl[2];
    if constexpr (MK != 0) {
#pragma unroll
      for (int fr = 0; fr < 2; ++fr) {
        int ar = r0 + (fr << 4) + la;
        if constexpr (MK == 1) lfrag(Mb, ar, kp, Ah[fr], Al[fr]);
        else gfrag(gAm, ar, kp, Ah[fr], Al[fr]);
      }
    }
#pragma unroll
    for (int fc = 0; fc < 2; ++fc) {
      int bc = c0 + (fc << 4) + la;
      if constexpr (MK == 3) gfrag(gBm, bc, kp, Bh[fc], Bl[fc]);
      else lfrag(Tb, bc, kp, Bh[fc], Bl[fc]);
    }
    bf16x8 Eh[ERN], El[ERN];
    if constexpr (ERS > 0) {
#pragma unroll
      for (int f = 0; f < ERS; ++f) {
        int er = (wr << 4) + (f << 6) + la;
        gfrag(gAe, er, kp, Eh[f], El[f]);
      }
    }
    bf16x8 Fh[2], Fl[2];
    if constexpr (HEC) {
#pragma unroll
      for (int e = 0; e < 2; ++e) {
        int ec = (wc << 5) + (e << 4) + la;
        gfrag(gBe, ec, kp, Fh[e], Fl[e]);
      }
    }
    if constexpr (MK == 1 || MK == 2) {
#pragma unroll
      for (int fr = 0; fr < 2; ++fr)
#pragma unroll
        for (int fc = 0; fc < 2; ++fc) {
          acc[fr][fc] = MF(Ah[fr], Bh[fc], acc[fr][fc]);
          acc[fr][fc] = MF(Ah[fr], Bl[fc], acc[fr][fc]);
          acc[fr][fc] = MF(Al[fr], Bh[fc], acc[fr][fc]);
          accT[fr][fc] = MF(Bh[fc], Ah[fr], accT[fr][fc]);
          accT[fr][fc] = MF(Bh[fc], Al[fr], accT[fr][fc]);
          accT[fr][fc] = MF(Bl[fc], Ah[fr], accT[fr][fc]);
        }
    }
    if constexpr (MK == 3) {
#pragma unroll
      for (int fr = 0; fr < 2; ++fr)
#pragma unroll
        for (int fc = 0; fc < 2; ++fc) {
          accT[fr][fc] = MF(Bh[fc], Ah[fr], accT[fr][fc]);
          accT[fr][fc] = MF(Bh[fc], Al[fr], accT[fr][fc]);
          accT[fr][fc] = MF(Bl[fc], Ah[fr], accT[fr][fc]);
        }
    }
    if constexpr (ERS > 0) {
#pragma unroll
      for (int f = 0; f < ERS; ++f)
#pragma unroll
        for (int fc = 0; fc < 2; ++fc) {
          accE[f][fc] = MF(Bh[fc], Eh[f], accE[f][fc]);
          accE[f][fc] = MF(Bh[fc], El[f], accE[f][fc]);
          accE[f][fc] = MF(Bl[fc], Eh[f], accE[f][fc]);
        }
    }
    if constexpr (HEC) {
#pragma unroll
      for (int fr = 0; fr < 2; ++fr)
#pragma unroll
        for (int e = 0; e < 2; ++e) {
          accC[fr][e] = MF(Ah[fr], Fh[e], accC[fr][e]);
          accC[fr][e] = MF(Ah[fr], Fl[e], accC[fr][e]);
          accC[fr][e] = MF(Al[fr], Fh[e], accC[fr][e]);
        }
    }
  }

  __syncthreads();  // all slot reads drained -> in-place writes safe

  if constexpr (MK == 1 || MK == 2) {
#pragma unroll
    for (int fr = 0; fr < 2; ++fr)
#pragma unroll
      for (int fc = 0; fc < 2; ++fc) {
        // accT: lane = row rr, cols cb..cb+3 -> M rows (+ optional dump)
        int rr = r0 + (fr << 4) + la;
        int cb = c0 + (fc << 4) + (g << 2);
        float v[4];
#pragma unroll
        for (int j = 0; j < 4; ++j) v[j] = accT[fr][fc][j];
        if constexpr (MK == 2) {
#pragma unroll
          for (int j = 0; j < 4; ++j)
            v[j] = c3 * (v[j] + bf2f(gU[rr * 128 + cb + j]) +
                         bf2f(gU[PLG + rr * 128 + cb + j])) -
                   ((rr == cb + j) ? 1.f : 0.f);
        }
        u16x4 hi, lo;
        pack4(v, hi, lo);
        *(u16x4*)(Mb + MIDX(rr, cb)) = hi;
        *(u16x4*)(Mb + PL + MIDX(rr, cb)) = lo;
        if constexpr (DUMP) {
          *(u16x4*)(gDump + rr * 128 + cb) = hi;
          *(u16x4*)(gDump + PLG + rr * 128 + cb) = lo;
        }
        // acc: lane = col cc, rows rb..rb+3 -> Bt cols
        int cc = c0 + (fc << 4) + la;
        int rb = r0 + (fr << 4) + (g << 2);
        float q[4];
#pragma unroll
        for (int j = 0; j < 4; ++j) q[j] = acc[fr][fc][j];
        if constexpr (MK == 2) {
#pragma unroll
          for (int j = 0; j < 4; ++j)
            q[j] = c3 * (q[j] + bf2f(gU[(rb + j) * 128 + cc]) +
                         bf2f(gU[PLG + (rb + j) * 128 + cc])) -
                   ((rb + j == cc) ? 1.f : 0.f);
        }
        u16x4 hi2, lo2;
        pack4(q, hi2, lo2);
        *(u16x4*)(Tb + MIDX(cc, rb)) = hi2;
        *(u16x4*)(Tb + PL + MIDX(cc, rb)) = lo2;
      }
  }
  if constexpr (MK == 3) {
#pragma unroll
    for (int fr = 0; fr < 2; ++fr)
#pragma unroll
      for (int fc = 0; fc < 2; ++fc) {
        int rr = r0 + (fr << 4) + la;
        int cb = c0 + (fc << 4) + (g << 2);
        f32x4 v = accT[fr][fc];
        *(float4*)(KvO + rr * 256 + kc0 + cb) = make_float4(v[0], v[1], v[2], v[3]);
      }
  }
  if constexpr (ERS > 0) {
#pragma unroll
    for (int f = 0; f < ERS; ++f) {
      int er = (wr << 4) + (f << 6) + la;
      if (er < ER) {
#pragma unroll
        for (int fc = 0; fc < 2; ++fc) {
          int cb = c0 + (fc << 4) + (g << 2);
          float v[4];
#pragma unroll
          for (int j = 0; j < 4; ++j) v[j] = accE[f][fc][j];
          if constexpr (M2) {
#pragma unroll
            for (int j = 0; j < 4; ++j)
              v[j] += bf2f(gT1[er * 128 + cb + j]) + bf2f(gT1[PLG + er * 128 + cb + j]) +
                      bf2f(gT2x[er * 128 + cb + j]) + bf2f(gT2x[PLG + er * 128 + cb + j]) +
                      ((er == cb + j) ? 1.f : 0.f);
          }
          u16x4 hi, lo;
          pack4(v, hi, lo);
          *(u16x4*)(gOe + (eR0 + er) * 128 + cb) = hi;
          *(u16x4*)(gOe + PLG + (eR0 + er) * 128 + cb) = lo;
        }
      }
    }
  }
  if constexpr (HEC) {
#pragma unroll
    for (int e = 0; e < 2; ++e) {
      int ec = (wc << 5) + (e << 4) + la;
      if (ec < EC) {
#pragma unroll
        for (int fr = 0; fr < 2; ++fr) {
          int rb = r0 + (fr << 4) + (g << 2);
          float v[4];
#pragma unroll
          for (int j = 0; j < 4; ++j) v[j] = accC[fr][e][j];
          u16x4 hi, lo;
          pack4(v, hi, lo);
          *(u16x4*)(gOc + (eC0 + ec) * 128 + rb) = hi;
          *(u16x4*)(gOc + PLG + (eC0 + ec) * 128 + rb) = lo;
        }
      }
    }
  }
}

// ---------------------------------------------------------------------------
// Whole chain in ONE 1024-thread block, 21 fused steps:
// stage T | T2 (+dump) | {T4 || U12} | ab | seed | 8x {sq || R-dbl} |
// 6x {sq || S-dbl} | S-dbl6 | 2x K=S*R (f32).
// ---------------------------------------------------------------------------
__global__ void __launch_bounds__(1024, 4) chain_k(const float* __restrict__ A,
                                                   const float* __restrict__ Bv,
                                                   const float* __restrict__ Cv,
                                                   const float* __restrict__ lstep,
                                                   u16* ws) {
  extern __shared__ u16 lds[];
  u16* gT  = ws;              // T rows, 2 planes
  u16* gT2 = ws + 65536;      // T2 rows
  u16* gU  = ws + 131072;     // U12 rows
  u16* rt  = ws + 196608;     // R^T rows (256x128)
  u16* gs  = ws + 262144;     // S rows (128x128)
  float* Kv = (float*)(ws + 327680);

  const int t = threadIdx.x;
  const float stp = expf(lstep[0]);
  const float alpha = 0.5f * stp / (1.f + stp);
  const float c3 = 2.f / (1.f + stp);
  u16* Mh = lds; u16* Ml = lds + PL; u16* Th = lds + 2 * PL; u16* Tl = lds + 3 * PL;

  // s0: T = alpha*(A+2I) -> LDS M + Bt (swizzled), gT rows
#pragma unroll
  for (int i = 0; i < 4; ++i) {
    int e4 = (t + (i << 10)) << 2;
    int r = e4 >> 7, c = e4 & 127;
    float4 av = *(const float4*)(A + e4);
    float vv[4] = {av.x, av.y, av.z, av.w};
    float tv[4];
#pragma unroll
    for (int j = 0; j < 4; ++j) tv[j] = alpha * (vv[j] + ((r == c + j) ? 2.f : 0.f));
    u16x4 hi, lo;
    pack4(tv, hi, lo);
    *(u16x4*)(Mh + MIDX(r, c)) = hi;
    *(u16x4*)(Ml + MIDX(r, c)) = lo;
    *(u16x4*)(gT + r * 128 + c) = hi;
    *(u16x4*)(gT + PLG + r * 128 + c) = lo;
#pragma unroll
    for (int j = 0; j < 4; ++j) {
      Th[MIDX(c + j, r)] = hi[j];
      Tl[MIDX(c + j, r)] = lo[j];
    }
  }

  // s1: T2 = T*T (in-place) + dump T2 rows -> gT2
  step<1,0,false,false,true>(lds, 0, 0, 0, 0.f, 0, 0, gT2,
                             0, 0, 0, 0, 0, 0, 0, 0, 0, 0);
  // s2: T4 = T2*T2 (in-place)  ||  U12 = T*T2 + T + T2 + I -> gU
  step<1,2,false,true,false>(lds, 0, 0, 0, 0.f, 0, 0, 0,
                             128, gT, gU, 0, gT, gT2, 0, 0, 0, 0);
  // s3: ab = c3*(U12*T4 + U12) - I (A = gU rows, in-place slot = pw0)
  step<2,0,false,false,false>(lds, gU, 0, gU, c3, 0, 0, 0,
                              0, 0, 0, 0, 0, 0, 0, 0, 0, 0);

  // seed: rt row0 = bb = (step/2)*(ab*B + B) ; gs row0 = C
  __syncthreads();
  if (t < 128) {
    float a2 = 0.f;
    for (int p = 0; p < 128; ++p)
      a2 = fmaf(bf2f(Mh[MIDX(t, p)]) + bf2f(Ml[MIDX(t, p)]), Bv[p], a2);
    float v = 0.5f * stp * (a2 + Bv[t]);
    u16 h = f2bf(v);
    rt[t] = h;
    rt[PLG + t] = f2bf(v - bf2f(h));
  } else if (t < 256) {
    float v = Cv[t - 128];
    u16 h = f2bf(v);
    gs[t - 128] = h;
    gs[PLG + t - 128] = f2bf(v - bf2f(h));
  }

  // s4..s11 (i=1..8): sq pw(i-1)->pw(i) || R-dbl k=i-1 (EC=2^k cols via rt)
  for (int i = 1; i <= 8; ++i) {
    int EC = 1 << (i - 1);
    step<1,0,true,false,false>(lds, 0, 0, 0, 0.f, 0, 0, 0,
                               0, 0, 0, 0, 0, 0, EC, rt, rt, EC);
  }
  // s12..s17 (i=9..14): sq || S-dbl j=i-9 (ER=2^j rows via gs)
  for (int i = 9; i <= 14; ++i) {
    int ER = 1 << (i - 9);
    step<1,1,false,false,false>(lds, 0, 0, 0, 0.f, 0, 0, 0,
                                ER, gs, gs, ER, 0, 0, 0, 0, 0, 0);
  }
  // s18: S-dbl j=6 (ER=64) using pw14 in slot, no main product
  step<0,1,false,false,false>(lds, 0, 0, 0, 0.f, 0, 0, 0,
                              64, gs, gs, 64, 0, 0, 0, 0, 0, 0);
  // s19/s20: K = S * R  (f32 out), columns 0..127 then 128..255
  step<3,0,false,false,false>(lds, gs, rt, 0, 0.f, Kv, 0, 0,
                              0, 0, 0, 0, 0, 0, 0, 0, 0, 0);
  step<3,0,false,false,false>(lds, gs, rt + 128 * 128, 0, 0.f, Kv, 128, 0,
                              0, 0, 0, 0, 0, 0, 0, 0, 0, 0);
}

// ---------------------------------------------------------------------------
// Conv partials: task (m, j), m<32, j<2(m+1): output tile m (1024 samples),
// K-chunk [j*512,(j+1)*512). 1056 blocks x 64 threads (1 wave), 16 outputs
// per thread -> VALU-bound (128 FMA-cyc : 24 LDS-cyc per 4 taps).
// ---------------------------------------------------------------------------
__global__ __launch_bounds__(64) void conv_k(const float* __restrict__ u,
                                             const float* __restrict__ Kv,
                                             float* __restrict__ Pp) {
  __shared__ __align__(16) float ks[512];
  __shared__ __align__(16) float usw[1536];

  int bid = blockIdx.x, tid = threadIdx.x;
  int m = (int)((sqrtf(4.f * (float)bid + 1.f) - 1.f) * 0.5f);
  while ((m + 1) * (m + 2) <= bid) ++m;
  while (m * (m + 1) > bid) --m;
  int j = bid - m * (m + 1);             // 0 .. 2m+1
  int w0 = (m << 10) - (j << 9) - 512;   // usw[li] = u[w0 + li]

  for (int idx = tid; idx < 512; idx += 64) ks[idx] = Kv[(j << 9) + idx];
  for (int idx = tid; idx < 1536; idx += 64) {
    int gi = w0 + idx;
    float v = (gi >= 0) ? u[gi] : 0.f;
    int b = idx >> 2, pb = b ^ ((b >> 3) & 7);
    usw[(pb << 2) | (idx & 3)] = v;
  }
  __syncthreads();

  int tb = tid << 4;
  float acc[16];
#pragma unroll
  for (int z = 0; z < 16; ++z) acc[z] = 0.f;

#define LD4(x) (*(const float4*)&usw[((((x) >> 2) ^ ((((x) >> 2) >> 3) & 7)) << 2)])
  float wf[20];
  {
    float4 a0 = LD4(508 + tb), a1 = LD4(512 + tb), a2 = LD4(516 + tb),
           a3 = LD4(520 + tb), a4 = LD4(524 + tb);
    wf[0] = a0.x; wf[1] = a0.y; wf[2] = a0.z; wf[3] = a0.w;
    wf[4] = a1.x; wf[5] = a1.y; wf[6] = a1.z; wf[7] = a1.w;
    wf[8] = a2.x; wf[9] = a2.y; wf[10] = a2.z; wf[11] = a2.w;
    wf[12] = a3.x; wf[13] = a3.y; wf[14] = a3.z; wf[15] = a3.w;
    wf[16] = a4.x; wf[17] = a4.y; wf[18] = a4.z; wf[19] = a4.w;
  }
  // acc[oi] += K[q+ds] * us[512 + tb + oi - q - ds];  wf[x] = us[512+tb-q-4+x]
  for (int q = 0; q < 512; q += 4) {
    float4 k4 = *(const float4*)&ks[q];
    float kk[4] = {k4.x, k4.y, k4.z, k4.w};
#pragma unroll
    for (int ds = 0; ds < 4; ++ds)
#pragma unroll
      for (int oi = 0; oi < 16; ++oi)
        acc[oi] = fmaf(kk[ds], wf[oi - ds + 4], acc[oi]);
    if (q < 508) {
#pragma unroll
      for (int z = 19; z >= 4; --z) wf[z] = wf[z - 4];
      float4 nw = LD4(504 + tb - q);
      wf[0] = nw.x; wf[1] = nw.y; wf[2] = nw.z; wf[3] = nw.w;
    }
  }
#undef LD4

  float* dst = Pp + (bid << 10) + tb;
#pragma unroll
  for (int z = 0; z < 16; z += 4)
    *(float4*)(dst + z) = make_float4(acc[z], acc[z + 1], acc[z + 2], acc[z + 3]);
}

// ---------------------------------------------------------------------------
// reduce: y[t] = D*u[t] + sum_{j<2(m+1)} Pp[(m(m+1)+j)*1024 + (t&1023)]
// ---------------------------------------------------------------------------
__global__ __launch_bounds__(256) void reduce_k(const float* __restrict__ Pp,
                                                const float* __restrict__ u,
                                                const float* __restrict__ D,
                                                float* __restrict__ y) {
  int t = blockIdx.x * 256 + threadIdx.x;
  if (t >= L_SEQ) return;
  int m = t >> 10;
  int nJ = 2 * (m + 1);
  const float* base = Pp + ((m * (m + 1)) << 10) + (t & 1023);
  float acc = D[0] * u[t];
  for (int j = 0; j < nJ; ++j) acc += base[j << 10];
  y[t] = acc;
}

// ---------------------------------------------------------------------------
// host. ws layout (bytes):
//   [0,131072) gT | [131072,262144) gT2 | [262144,393216) gU |
//   [393216,524288) rt | [524288,655360) gs | [655360,786432) Kv f32 |
//   [786432,5111808) Pp f32[1056*1024]   (== proven round-6/7/8 ws extent)
// ---------------------------------------------------------------------------
extern "C" void kernel_launch(void* const* d_in, const int* in_sizes, int n_in,
                              void* d_out, int out_size, void* d_ws, size_t ws_size,
                              hipStream_t stream) {
  (void)in_sizes; (void)n_in; (void)out_size; (void)ws_size;
  const float* u     = (const float*)d_in[0];
  const float* A     = (const float*)d_in[1];
  const float* B     = (const float*)d_in[2];
  const float* C     = (const float*)d_in[3];
  const float* D     = (const float*)d_in[4];
  const float* lstep = (const float*)d_in[5];
  float* y = (float*)d_out;
  u16* ws = (u16*)d_ws;

  float* Kv = (float*)((char*)d_ws + 655360);
  float* Pp = (float*)((char*)d_ws + 786432);

  (void)hipFuncSetAttribute((const void*)chain_k,
                            hipFuncAttributeMaxDynamicSharedMemorySize, 131072);
  hipLaunchKernelGGL(chain_k, dim3(1), dim3(1024), 131072, stream, A, B, C, lstep, ws);
  hipLaunchKernelGGL(conv_k, dim3(1056), dim3(64), 0, stream, u, Kv, Pp);
  hipLaunchKernelGGL(reduce_k, dim3(L_SEQ / 256), dim3(256), 0, stream, Pp, u, D, y);
}

// Round 10
// 236.670 us; speedup vs baseline: 1.3776x; 1.3776x over previous
//
#include <hip/hip_runtime.h>
#include <math.h>

#define L_SEQ 32768
#define PL 16384      // u16 per LDS plane (128x128 swizzled)
#define PLG 32768     // u16 plane stride for ALL global chain matrices

typedef unsigned short u16;
typedef float f32x4 __attribute__((ext_vector_type(4)));
typedef short bf16x8 __attribute__((ext_vector_type(8)));
typedef u16 u16x4 __attribute__((ext_vector_type(4)));

__device__ __forceinline__ u16 f2bf(float x) {
  unsigned u = __float_as_uint(x);
  u = u + 0x7FFFu + ((u >> 16) & 1u);
  return (u16)(u >> 16);
}
__device__ __forceinline__ float bf2f(u16 h) { return __uint_as_float(((unsigned)h) << 16); }
__device__ __forceinline__ int MIDX(int r, int c) { return (r << 7) + (c ^ ((r & 7) << 3)); }
__device__ __forceinline__ f32x4 MF(bf16x8 a, bf16x8 b, f32x4 c) {
  return __builtin_amdgcn_mfma_f32_16x16x32_bf16(a, b, c, 0, 0, 0);
}
__device__ __forceinline__ void gfrag(const u16* g, int row, int kp, bf16x8& h, bf16x8& l) {
  h = *(const bf16x8*)(g + row * 128 + kp);
  l = *(const bf16x8*)(g + PLG + row * 128 + kp);
}
__device__ __forceinline__ void lfrag(const u16* base, int row, int kp, bf16x8& h, bf16x8& l) {
  h = *(const bf16x8*)(base + MIDX(row, kp));
  l = *(const bf16x8*)(base + PL + MIDX(row, kp));
}
__device__ __forceinline__ void pack4(const float* v, u16x4& hi, u16x4& lo) {
#pragma unroll
  for (int j = 0; j < 4; ++j) {
    u16 h = f2bf(v[j]);
    hi[j] = h;
    lo[j] = f2bf(v[j] - bf2f(h));
  }
}

// ---------------------------------------------------------------------------
// One fused step on a 1024-thread block (16 waves, 4x4 grid of 32x32 tiles).
// Main product C = A(128x128)*B(128x128), fp32 via 3 bf16 MFMAs (hi/lo planes).
// MK: 0 none | 1 in-place slot update (acc->Bt, accT->M) | 2 same + MODE4
//     (v = c3*(v + U12) - I, U12 from gU rows) with A from gU global
// ERS extra-row slots: rides S-dbl / U12 on the shared B operand; out rows to
//     gOe at eR0+er; M2 adds T+T2+I (gT1,gT2x rows).
// HEC extra cols: rides R-dbl on the shared A operand, B streamed from gBe
//     rows; out transposed to gOc at eC0+ec.
// DUMP: also write accT rows to gDump (row-major) - used to spill T2.
// ---------------------------------------------------------------------------
template<int MK, int ERS, bool HEC, bool M2, bool DUMP>
__device__ void step(u16* lds,
                     const u16* gAm, const u16* gU, float c3, u16* gDump,
                     int ER, const u16* gAe, u16* gOe, int eR0,
                     const u16* gT1, const u16* gT2x,
                     int EC, const u16* gBe, u16* gOc, int eC0) {
  u16* Mb = lds;
  u16* Tb = lds + 2 * PL;
  const int t = threadIdx.x, lane = t & 63, la = lane & 15, g = lane >> 4;
  const int w = t >> 6, wr = w >> 2, wc = w & 3;
  const int r0 = wr << 5, c0 = wc << 5;
  constexpr int ERN = (ERS > 0) ? ERS : 1;

  __syncthreads();  // operands (LDS slot + prior global writes) ready

  f32x4 acc[2][2], accT[2][2], accE[ERN][2], accC[2][2];
#pragma unroll
  for (int i = 0; i < 2; ++i)
#pragma unroll
    for (int j = 0; j < 2; ++j) {
      acc[i][j] = (f32x4){0.f, 0.f, 0.f, 0.f};
      accT[i][j] = (f32x4){0.f, 0.f, 0.f, 0.f};
      accC[i][j] = (f32x4){0.f, 0.f, 0.f, 0.f};
    }
#pragma unroll
  for (int f = 0; f < ERN; ++f)
#pragma unroll
    for (int j = 0; j < 2; ++j) accE[f][j] = (f32x4){0.f, 0.f, 0.f, 0.f};

#pragma unroll
  for (int kb = 0; kb < 4; ++kb) {
    const int kp = (kb << 5) + (g << 3);
    bf16x8 Ah[2], Al[2], Bh[2], Bl[2];
    if constexpr (MK != 0) {
#pragma unroll
      for (int fr = 0; fr < 2; ++fr) {
        int ar = r0 + (fr << 4) + la;
        if constexpr (MK == 1) lfrag(Mb, ar, kp, Ah[fr], Al[fr]);
        else gfrag(gAm, ar, kp, Ah[fr], Al[fr]);
      }
    }
#pragma unroll
    for (int fc = 0; fc < 2; ++fc) {
      int bc = c0 + (fc << 4) + la;
      lfrag(Tb, bc, kp, Bh[fc], Bl[fc]);
    }
    bf16x8 Eh[ERN], El[ERN];
    if constexpr (ERS > 0) {
#pragma unroll
      for (int f = 0; f < ERS; ++f) {
        int er = (wr << 4) + (f << 6) + la;
        gfrag(gAe, er, kp, Eh[f], El[f]);
      }
    }
    bf16x8 Fh[2], Fl[2];
    if constexpr (HEC) {
#pragma unroll
      for (int e = 0; e < 2; ++e) {
        int ec = (wc << 5) + (e << 4) + la;
        gfrag(gBe, ec, kp, Fh[e], Fl[e]);
      }
    }
    if constexpr (MK != 0) {
#pragma unroll
      for (int fr = 0; fr < 2; ++fr)
#pragma unroll
        for (int fc = 0; fc < 2; ++fc) {
          acc[fr][fc] = MF(Ah[fr], Bh[fc], acc[fr][fc]);
          acc[fr][fc] = MF(Ah[fr], Bl[fc], acc[fr][fc]);
          acc[fr][fc] = MF(Al[fr], Bh[fc], acc[fr][fc]);
          accT[fr][fc] = MF(Bh[fc], Ah[fr], accT[fr][fc]);
          accT[fr][fc] = MF(Bh[fc], Al[fr], accT[fr][fc]);
          accT[fr][fc] = MF(Bl[fc], Ah[fr], accT[fr][fc]);
        }
    }
    if constexpr (ERS > 0) {
#pragma unroll
      for (int f = 0; f < ERS; ++f)
#pragma unroll
        for (int fc = 0; fc < 2; ++fc) {
          accE[f][fc] = MF(Bh[fc], Eh[f], accE[f][fc]);
          accE[f][fc] = MF(Bh[fc], El[f], accE[f][fc]);
          accE[f][fc] = MF(Bl[fc], Eh[f], accE[f][fc]);
        }
    }
    if constexpr (HEC) {
#pragma unroll
      for (int fr = 0; fr < 2; ++fr)
#pragma unroll
        for (int e = 0; e < 2; ++e) {
          accC[fr][e] = MF(Ah[fr], Fh[e], accC[fr][e]);
          accC[fr][e] = MF(Ah[fr], Fl[e], accC[fr][e]);
          accC[fr][e] = MF(Al[fr], Fh[e], accC[fr][e]);
        }
    }
  }

  __syncthreads();  // all slot reads drained -> in-place writes safe

  if constexpr (MK != 0) {
#pragma unroll
    for (int fr = 0; fr < 2; ++fr)
#pragma unroll
      for (int fc = 0; fc < 2; ++fc) {
        // accT: lane = row rr, cols cb..cb+3 -> M rows (+ optional dump)
        int rr = r0 + (fr << 4) + la;
        int cb = c0 + (fc << 4) + (g << 2);
        float v[4];
#pragma unroll
        for (int j = 0; j < 4; ++j) v[j] = accT[fr][fc][j];
        if constexpr (MK == 2) {
#pragma unroll
          for (int j = 0; j < 4; ++j)
            v[j] = c3 * (v[j] + bf2f(gU[rr * 128 + cb + j]) +
                         bf2f(gU[PLG + rr * 128 + cb + j])) -
                   ((rr == cb + j) ? 1.f : 0.f);
        }
        u16x4 hi, lo;
        pack4(v, hi, lo);
        *(u16x4*)(Mb + MIDX(rr, cb)) = hi;
        *(u16x4*)(Mb + PL + MIDX(rr, cb)) = lo;
        if constexpr (DUMP) {
          *(u16x4*)(gDump + rr * 128 + cb) = hi;
          *(u16x4*)(gDump + PLG + rr * 128 + cb) = lo;
        }
        // acc: lane = col cc, rows rb..rb+3 -> Bt cols
        int cc = c0 + (fc << 4) + la;
        int rb = r0 + (fr << 4) + (g << 2);
        float q[4];
#pragma unroll
        for (int j = 0; j < 4; ++j) q[j] = acc[fr][fc][j];
        if constexpr (MK == 2) {
#pragma unroll
          for (int j = 0; j < 4; ++j)
            q[j] = c3 * (q[j] + bf2f(gU[(rb + j) * 128 + cc]) +
                         bf2f(gU[PLG + (rb + j) * 128 + cc])) -
                   ((rb + j == cc) ? 1.f : 0.f);
        }
        u16x4 hi2, lo2;
        pack4(q, hi2, lo2);
        *(u16x4*)(Tb + MIDX(cc, rb)) = hi2;
        *(u16x4*)(Tb + PL + MIDX(cc, rb)) = lo2;
      }
  }
  if constexpr (ERS > 0) {
#pragma unroll
    for (int f = 0; f < ERS; ++f) {
      int er = (wr << 4) + (f << 6) + la;
      if (er < ER) {
#pragma unroll
        for (int fc = 0; fc < 2; ++fc) {
          int cb = c0 + (fc << 4) + (g << 2);
          float v[4];
#pragma unroll
          for (int j = 0; j < 4; ++j) v[j] = accE[f][fc][j];
          if constexpr (M2) {
            u16x4 t1h = *(const u16x4*)(gT1 + er * 128 + cb);
            u16x4 t1l = *(const u16x4*)(gT1 + PLG + er * 128 + cb);
            u16x4 t2h = *(const u16x4*)(gT2x + er * 128 + cb);
            u16x4 t2l = *(const u16x4*)(gT2x + PLG + er * 128 + cb);
#pragma unroll
            for (int j = 0; j < 4; ++j)
              v[j] += bf2f(t1h[j]) + bf2f(t1l[j]) + bf2f(t2h[j]) + bf2f(t2l[j]) +
                      ((er == cb + j) ? 1.f : 0.f);
          }
          u16x4 hi, lo;
          pack4(v, hi, lo);
          *(u16x4*)(gOe + (eR0 + er) * 128 + cb) = hi;
          *(u16x4*)(gOe + PLG + (eR0 + er) * 128 + cb) = lo;
        }
      }
    }
  }
  if constexpr (HEC) {
#pragma unroll
    for (int e = 0; e < 2; ++e) {
      int ec = (wc << 5) + (e << 4) + la;
      if (ec < EC) {
#pragma unroll
        for (int fr = 0; fr < 2; ++fr) {
          int rb = r0 + (fr << 4) + (g << 2);
          float v[4];
#pragma unroll
          for (int j = 0; j < 4; ++j) v[j] = accC[fr][e][j];
          u16x4 hi, lo;
          pack4(v, hi, lo);
          *(u16x4*)(gOc + (eC0 + ec) * 128 + rb) = hi;
          *(u16x4*)(gOc + PLG + (eC0 + ec) * 128 + rb) = lo;
        }
      }
    }
  }
}

// ---------------------------------------------------------------------------
// Chain: 2 independent 1024-thread blocks. Both run Neumann (3 products):
//   s1: T2 = T*T (+dump T2) ; s2: T4+I  || ERS U12 = T*T2+T+T2+I ;
//   s3: ab = c3*(U12*(I+T4)) - I  [A = gU rows]   (wait: MK2 computes
//   c3*(A*B + U12-addend): here B = I+T4 folded by s2's epilogue? No -
//   we keep r9 semantics: s2 main = T4, s3 = c3*(U12*T4 + U12) - I.)
// block 0: seed bb -> rt row0, then 8x {sq pw(k-1)->pw(k) || R-dbl k-1}
// block 1: seed C -> gs row0, then 14x sq (last 6 carry S-dbl) + S-dbl(64)
// amdgpu_waves_per_eu(1,4): cap 4 waves/EU -> 128-VGPR budget (kill spills).
// ---------------------------------------------------------------------------
__global__ void __launch_bounds__(1024)
__attribute__((amdgpu_waves_per_eu(1, 4)))
chain_k(const float* __restrict__ A, const float* __restrict__ Bv,
        const float* __restrict__ Cv, const float* __restrict__ lstep,
        u16* ws) {
  extern __shared__ u16 lds[];
  const int bid = blockIdx.x;
  u16* gT  = ws + bid * 98304;     // per-block: T rows (2 planes)
  u16* gT2 = gT + 32768;           // T2 rows
  u16* gU  = gT + 65536;           // U12 rows
  u16* rt  = ws + 196608;          // R^T rows (256x128), planes +PLG
  u16* gs  = ws + 262144;          // S rows (128x128), planes +PLG

  const int t = threadIdx.x;
  const float stp = expf(lstep[0]);
  const float alpha = 0.5f * stp / (1.f + stp);
  const float c3 = 2.f / (1.f + stp);
  u16* Mh = lds; u16* Ml = lds + PL; u16* Th = lds + 2 * PL; u16* Tl = lds + 3 * PL;

  // s0: T = alpha*(A+2I) -> LDS M + Bt (swizzled), gT rows
#pragma unroll
  for (int i = 0; i < 4; ++i) {
    int e4 = (t + (i << 10)) << 2;
    int r = e4 >> 7, c = e4 & 127;
    float4 av = *(const float4*)(A + e4);
    float vv[4] = {av.x, av.y, av.z, av.w};
    float tv[4];
#pragma unroll
    for (int j = 0; j < 4; ++j) tv[j] = alpha * (vv[j] + ((r == c + j) ? 2.f : 0.f));
    u16x4 hi, lo;
    pack4(tv, hi, lo);
    *(u16x4*)(Mh + MIDX(r, c)) = hi;
    *(u16x4*)(Ml + MIDX(r, c)) = lo;
    *(u16x4*)(gT + r * 128 + c) = hi;
    *(u16x4*)(gT + PLG + r * 128 + c) = lo;
#pragma unroll
    for (int j = 0; j < 4; ++j) {
      Th[MIDX(c + j, r)] = hi[j];
      Tl[MIDX(c + j, r)] = lo[j];
    }
  }

  // s1: T2 = T*T (in-place) + dump T2 rows -> gT2
  step<1,0,false,false,true>(lds, 0, 0, 0.f, gT2,
                             0, 0, 0, 0, 0, 0, 0, 0, 0, 0);
  // s2: T4 = T2*T2 (in-place)  ||  U12 = T*T2 + T + T2 + I -> gU
  step<1,2,false,true,false>(lds, 0, 0, 0.f, 0,
                             128, gT, gU, 0, gT, gT2, 0, 0, 0, 0);
  // s3: ab = c3*(U12*T4 + U12) - I  (A = gU rows, in-place slot = pw0)
  step<2,0,false,false,false>(lds, gU, gU, c3, 0,
                              0, 0, 0, 0, 0, 0, 0, 0, 0, 0);

  if (bid == 0) {
    // seed: rt row0 = bb = (step/2)*(ab*B + B)
    __syncthreads();
    if (t < 128) {
      float a2 = 0.f;
      for (int p = 0; p < 128; ++p)
        a2 = fmaf(bf2f(Mh[MIDX(t, p)]) + bf2f(Ml[MIDX(t, p)]), Bv[p], a2);
      float v = 0.5f * stp * (a2 + Bv[t]);
      u16 h = f2bf(v);
      rt[t] = h;
      rt[PLG + t] = f2bf(v - bf2f(h));
    }
    // 8x: sq pw(i-1)->pw(i) || R-dbl k=i-1 (EC=2^k cols via rt)
    for (int i = 1; i <= 8; ++i) {
      int EC = 1 << (i - 1);
      step<1,0,true,false,false>(lds, 0, 0, 0.f, 0,
                                 0, 0, 0, 0, 0, 0, EC, rt, rt, EC);
    }
  } else {
    // seed: gs row0 = C
    __syncthreads();
    if (t < 128) {
      float v = Cv[t];
      u16 h = f2bf(v);
      gs[t] = h;
      gs[PLG + t] = f2bf(v - bf2f(h));
    }
    // sq #1..#8 (plain)
    for (int i = 1; i <= 8; ++i)
      step<1,0,false,false,false>(lds, 0, 0, 0.f, 0,
                                  0, 0, 0, 0, 0, 0, 0, 0, 0, 0);
    // sq #9..#14 carry S-dbl j=0..5 (Y = pw(8+j) during MFMA)
    for (int j = 0; j <= 5; ++j) {
      int ER = 1 << j;
      step<1,1,false,false,false>(lds, 0, 0, 0.f, 0,
                                  ER, gs, gs, ER, 0, 0, 0, 0, 0, 0);
    }
    // S-dbl j=6 (ER=64) using Y = pw14, no main product
    step<0,1,false,false,false>(lds, 0, 0, 0.f, 0,
                                64, gs, gs, 64, 0, 0, 0, 0, 0, 0);
  }
}

// ---------------------------------------------------------------------------
// K[t1*256 + t0] = S[t1] . R[:,t0]  (rt = R^T rows; planes at +PLG)
// ---------------------------------------------------------------------------
__global__ __launch_bounds__(256) void kmat_k(const u16* __restrict__ gs,
                                              const u16* __restrict__ rt,
                                              float* __restrict__ Kv) {
  __shared__ float srow[128];
  int t1 = blockIdx.x, t0 = threadIdx.x;
  if (t0 < 128)
    srow[t0] = bf2f(gs[t1 * 128 + t0]) + bf2f(gs[PLG + t1 * 128 + t0]);
  __syncthreads();
  const u16* rh = rt + t0 * 128;
  const u16* rl = rt + PLG + t0 * 128;
  float acc = 0.f;
#pragma unroll 4
  for (int p = 0; p < 128; p += 8) {
    uint4 qh = *(const uint4*)(rh + p);
    uint4 ql = *(const uint4*)(rl + p);
    unsigned dh[4] = {qh.x, qh.y, qh.z, qh.w};
    unsigned dl[4] = {ql.x, ql.y, ql.z, ql.w};
#pragma unroll
    for (int j = 0; j < 4; ++j) {
      acc = fmaf(srow[p + 2 * j],     bf2f((u16)dh[j]) + bf2f((u16)dl[j]), acc);
      acc = fmaf(srow[p + 2 * j + 1],
                 bf2f((u16)(dh[j] >> 16)) + bf2f((u16)(dl[j] >> 16)), acc);
    }
  }
  Kv[t1 * 256 + t0] = acc;
}

// ---------------------------------------------------------------------------
// Conv partials: task (m, j), m<32, j<2(m+1): output tile m (1024 samples),
// K-chunk [j*512,(j+1)*512). 1056 blocks x 64 threads, 16 outputs/thread.
// ---------------------------------------------------------------------------
__global__ __launch_bounds__(64) void conv_k(const float* __restrict__ u,
                                             const float* __restrict__ Kv,
                                             float* __restrict__ Pp) {
  __shared__ __align__(16) float ks[512];
  __shared__ __align__(16) float usw[1536];

  int bid = blockIdx.x, tid = threadIdx.x;
  int m = (int)((sqrtf(4.f * (float)bid + 1.f) - 1.f) * 0.5f);
  while ((m + 1) * (m + 2) <= bid) ++m;
  while (m * (m + 1) > bid) --m;
  int j = bid - m * (m + 1);             // 0 .. 2m+1
  int w0 = (m << 10) - (j << 9) - 512;   // usw[li] = u[w0 + li]

  for (int idx = tid; idx < 512; idx += 64) ks[idx] = Kv[(j << 9) + idx];
  for (int idx = tid; idx < 1536; idx += 64) {
    int gi = w0 + idx;
    float v = (gi >= 0) ? u[gi] : 0.f;
    int b = idx >> 2, pb = b ^ ((b >> 3) & 7);
    usw[(pb << 2) | (idx & 3)] = v;
  }
  __syncthreads();

  int tb = tid << 4;
  float acc[16];
#pragma unroll
  for (int z = 0; z < 16; ++z) acc[z] = 0.f;

#define LD4(x) (*(const float4*)&usw[((((x) >> 2) ^ ((((x) >> 2) >> 3) & 7)) << 2)])
  float wf[20];
  {
    float4 a0 = LD4(508 + tb), a1 = LD4(512 + tb), a2 = LD4(516 + tb),
           a3 = LD4(520 + tb), a4 = LD4(524 + tb);
    wf[0] = a0.x; wf[1] = a0.y; wf[2] = a0.z; wf[3] = a0.w;
    wf[4] = a1.x; wf[5] = a1.y; wf[6] = a1.z; wf[7] = a1.w;
    wf[8] = a2.x; wf[9] = a2.y; wf[10] = a2.z; wf[11] = a2.w;
    wf[12] = a3.x; wf[13] = a3.y; wf[14] = a3.z; wf[15] = a3.w;
    wf[16] = a4.x; wf[17] = a4.y; wf[18] = a4.z; wf[19] = a4.w;
  }
  for (int q = 0; q < 512; q += 4) {
    float4 k4 = *(const float4*)&ks[q];
    float kk[4] = {k4.x, k4.y, k4.z, k4.w};
#pragma unroll
    for (int ds = 0; ds < 4; ++ds)
#pragma unroll
      for (int oi = 0; oi < 16; ++oi)
        acc[oi] = fmaf(kk[ds], wf[oi - ds + 4], acc[oi]);
    if (q < 508) {
#pragma unroll
      for (int z = 19; z >= 4; --z) wf[z] = wf[z - 4];
      float4 nw = LD4(504 + tb - q);
      wf[0] = nw.x; wf[1] = nw.y; wf[2] = nw.z; wf[3] = nw.w;
    }
  }
#undef LD4

  float* dst = Pp + (bid << 10) + tb;
#pragma unroll
  for (int z = 0; z < 16; z += 4)
    *(float4*)(dst + z) = make_float4(acc[z], acc[z + 1], acc[z + 2], acc[z + 3]);
}

// ---------------------------------------------------------------------------
// reduce: y[t] = D*u[t] + sum_{j<2(m+1)} Pp[(m(m+1)+j)*1024 + (t&1023)]
// ---------------------------------------------------------------------------
__global__ __launch_bounds__(256) void reduce_k(const float* __restrict__ Pp,
                                                const float* __restrict__ u,
                                                const float* __restrict__ D,
                                                float* __restrict__ y) {
  int t = blockIdx.x * 256 + threadIdx.x;
  if (t >= L_SEQ) return;
  int m = t >> 10;
  int nJ = 2 * (m + 1);
  const float* base = Pp + ((m * (m + 1)) << 10) + (t & 1023);
  float acc = D[0] * u[t];
  for (int j = 0; j < nJ; ++j) acc += base[j << 10];
  y[t] = acc;
}

// ---------------------------------------------------------------------------
// host. ws layout (u16 units unless noted):
//   [0,196608)        per-block Neumann scratch (2 x 98304: gT|gT2|gU)
//   [196608,262144)   rt (R^T, 256x128, planes +32768)
//   [262144,311296)   gs (S, 128x128, planes +32768)
//   byte 622592:      Kv f32[32768]
//   byte 753664:      Pp f32[1056*1024]   (end 5079040 <= proven ws extent)
// ---------------------------------------------------------------------------
extern "C" void kernel_launch(void* const* d_in, const int* in_sizes, int n_in,
                              void* d_out, int out_size, void* d_ws, size_t ws_size,
                              hipStream_t stream) {
  (void)in_sizes; (void)n_in; (void)out_size; (void)ws_size;
  const float* u     = (const float*)d_in[0];
  const float* A     = (const float*)d_in[1];
  const float* B     = (const float*)d_in[2];
  const float* C     = (const float*)d_in[3];
  const float* D     = (const float*)d_in[4];
  const float* lstep = (const float*)d_in[5];
  float* y = (float*)d_out;
  u16* ws = (u16*)d_ws;

  u16* rt = ws + 196608;
  u16* gs = ws + 262144;
  float* Kv = (float*)((char*)d_ws + 622592);
  float* Pp = (float*)((char*)d_ws + 753664);

  (void)hipFuncSetAttribute((const void*)chain_k,
                            hipFuncAttributeMaxDynamicSharedMemorySize, 131072);
  hipLaunchKernelGGL(chain_k, dim3(2), dim3(1024), 131072, stream, A, B, C, lstep, ws);
  hipLaunchKernelGGL(kmat_k, dim3(128), dim3(256), 0, stream, gs, rt, Kv);
  hipLaunchKernelGGL(conv_k, dim3(1056), dim3(64), 0, stream, u, Kv, Pp);
  hipLaunchKernelGGL(reduce_k, dim3(L_SEQ / 256), dim3(256), 0, stream, Pp, u, D, y);
}